// Round 8
// baseline (1039.965 us; speedup 1.0000x reference)
//
#include <hip/hip_runtime.h>
#include <math.h>

#define N_NODES 20000
#define T_STEPS 8
#define E_EDGES 640000
#define TN (T_STEPS * N_NODES)   // 160000
#define TE (T_STEPS * E_EDGES)   // 5120000
#define HDIM 32
#define HEADS 2
#define NPB 8                    // nodes per block for lane-parallel node kernels
#define SCAN_BLOCKS 625          // TN / 256 exactly
#define GB 32                    // histogram blocks per timestep
#define CHUNK (E_EDGES / GB)     // 20000 edges per histogram block
#define NPAIR (N_NODES / 2)      // packed bins per timestep
#define GNT 4                    // GRU nodes per thread-group (named scalars only!)
#define GNB (8 * GNT)            // GRU nodes per block = 32 (625 blocks exactly)

__device__ __forceinline__ float lrelu02(float v) { return v > 0.f ? v : 0.2f * v; }
__device__ __forceinline__ float eluf(float v) { return v > 0.f ? v : expm1f(v); }
__device__ __forceinline__ float sigmoidf(float v) { return 1.f / (1.f + expf(-v)); }

__device__ __forceinline__ float lane32_sum(float v) {
    v += __shfl_xor(v, 16);
    v += __shfl_xor(v, 8);
    v += __shfl_xor(v, 4);
    v += __shfl_xor(v, 2);
    v += __shfl_xor(v, 1);
    return v;
}
__device__ __forceinline__ float lane64_sum(float v) {
    v += __shfl_xor(v, 32);
    return lane32_sum(v);
}

// ---- precompute S_s1[2], S_d1[2] (rank-1 GAT1 attention constants) ----
__global__ void k_prep(const float* __restrict__ W1, const float* __restrict__ as1,
                       const float* __restrict__ ad1, float* __restrict__ S4) {
    if (threadIdx.x == 0 && blockIdx.x == 0) {
        for (int hd = 0; hd < HEADS; ++hd) {
            float ss = 0.f, sd = 0.f;
            for (int c = 0; c < HDIM; ++c) {
                ss += W1[hd * HDIM + c] * as1[hd * HDIM + c];
                sd += W1[hd * HDIM + c] * ad1[hd * HDIM + c];
            }
            S4[hd] = ss;
            S4[HEADS + hd] = sd;
        }
    }
}

// ---- pass A: per-block LDS histogram + local rank (NO global atomics) ----
__global__ void k_hist(const int* __restrict__ ei, int* __restrict__ hist,
                       unsigned char* __restrict__ rank) {
    __shared__ int lh[NPAIR];  // 40 KB
    int t = blockIdx.y, b = blockIdx.x;
    for (int i = threadIdx.x; i < NPAIR; i += blockDim.x) lh[i] = 0;
    __syncthreads();
    const int* dstp = ei + (size_t)t * 2 * E_EDGES + E_EDGES + b * CHUNK;
    unsigned char* rk = rank + (size_t)t * E_EDGES + b * CHUNK;
    for (int j = threadIdx.x; j < CHUNK; j += blockDim.x) {
        int dst = dstp[j];
        int old = atomicAdd(&lh[dst >> 1], (dst & 1) ? 65536 : 1);
        rk[j] = (unsigned char)((old >> (16 * (dst & 1))) & 0xffff);
    }
    __syncthreads();
    int* hp = hist + ((size_t)t * GB + b) * NPAIR;
    for (int i = threadIdx.x; i < NPAIR; i += blockDim.x) hp[i] = lh[i];
}

// ---- pass B: per-(t,dst) prefix over blocks -> base (packed) + totals ----
__global__ void k_blkpre(const int* __restrict__ hist, int* __restrict__ base,
                         int* __restrict__ cnt) {
    int i = blockIdx.x * blockDim.x + threadIdx.x;  // (t, pair)
    if (i >= T_STEPS * NPAIR) return;
    int t = i / NPAIR, pr = i % NPAIR;
    int a0 = 0, a1 = 0;
    for (int b = 0; b < GB; ++b) {
        size_t idx = ((size_t)t * GB + b) * NPAIR + pr;
        int v = hist[idx];
        base[idx] = a0 | (a1 << 16);
        a0 += v & 0xffff;
        a1 += (v >> 16) & 0xffff;
    }
    cnt[t * N_NODES + 2 * pr] = a0;
    cnt[t * N_NODES + 2 * pr + 1] = a1;
}

// ---- scan (exclusive) over cnt[TN] -> row[TN+1] ----
__global__ void k_scan_a(const int* __restrict__ cnt, int* __restrict__ bsum) {
    __shared__ int s[256];
    int i = blockIdx.x * 256 + threadIdx.x;
    s[threadIdx.x] = (i < TN) ? cnt[i] : 0;
    __syncthreads();
    for (int off = 128; off > 0; off >>= 1) {
        if (threadIdx.x < off) s[threadIdx.x] += s[threadIdx.x + off];
        __syncthreads();
    }
    if (threadIdx.x == 0) bsum[blockIdx.x] = s[0];
}

__global__ void k_scan_b(const int* __restrict__ bsum, int* __restrict__ bpre) {
    __shared__ int s[256];
    __shared__ int carry;
    if (threadIdx.x == 0) carry = 0;
    __syncthreads();
    for (int base = 0; base < SCAN_BLOCKS; base += 256) {
        int i = base + threadIdx.x;
        int v = (i < SCAN_BLOCKS) ? bsum[i] : 0;
        s[threadIdx.x] = v;
        __syncthreads();
        for (int off = 1; off < 256; off <<= 1) {
            int add = (threadIdx.x >= off) ? s[threadIdx.x - off] : 0;
            __syncthreads();
            s[threadIdx.x] += add;
            __syncthreads();
        }
        if (i < SCAN_BLOCKS) bpre[i] = carry + s[threadIdx.x] - v;  // exclusive
        __syncthreads();
        if (threadIdx.x == 0) carry += s[255];
        __syncthreads();
    }
}

__global__ void k_scan_c(const int* __restrict__ cnt, const int* __restrict__ bpre,
                         int* __restrict__ row) {
    __shared__ int s[256];
    int i = blockIdx.x * 256 + threadIdx.x;
    int v = (i < TN) ? cnt[i] : 0;
    s[threadIdx.x] = v;
    __syncthreads();
    for (int off = 1; off < 256; off <<= 1) {
        int add = (threadIdx.x >= off) ? s[threadIdx.x - off] : 0;
        __syncthreads();
        s[threadIdx.x] += add;
        __syncthreads();
    }
    if (i < TN) row[i] = bpre[blockIdx.x] + s[threadIdx.x] - v;
    if (blockIdx.x == 0 && threadIdx.x == 0) row[TN] = TE;
}

// ---- pass C: scatter src into dst-sorted order (plain stores) ----
__global__ void k_scatter(const int* __restrict__ ei, const unsigned char* __restrict__ rank,
                          const int* __restrict__ row, const int* __restrict__ base,
                          unsigned short* __restrict__ es) {
    int j = blockIdx.x * blockDim.x + threadIdx.x;
    int t = blockIdx.y;
    if (j >= E_EDGES) return;
    size_t eb = (size_t)t * 2 * E_EDGES;
    int src = ei[eb + j];
    int dst = ei[eb + E_EDGES + j];
    int b = j / CHUNK;
    int bs = base[((size_t)t * GB + b) * NPAIR + (dst >> 1)];
    bs = (bs >> (16 * (dst & 1))) & 0xffff;
    int r = rank[(size_t)t * E_EDGES + j];
    es[row[t * N_NODES + dst] + bs + r] = (unsigned short)src;
}

// ---- GAT1 reduce: one wave per (t,dst), register accumulation ----
__global__ void k_gat1red(const unsigned short* __restrict__ es, const int* __restrict__ row,
                          const float* __restrict__ x, const float* __restrict__ S4,
                          float* __restrict__ inv) {
    int wid = (blockIdx.x * blockDim.x + threadIdx.x) >> 6;  // (t,dst) bin
    int lane = threadIdx.x & 63;
    if (wid >= TN) return;
    int t = wid / N_NODES;
    int start = row[wid], end = row[wid + 1];
    float Ss0 = S4[0], Ss1 = S4[1], Sd0 = S4[2], Sd1 = S4[3];
    float xd = x[wid];
    float d0 = 0.f, n0 = 0.f, d1 = 0.f, n1 = 0.f;
    const float* xt = x + (size_t)t * N_NODES;
    for (int p = start + lane; p < end; p += 64) {
        float xs = xt[es[p]];
        float w0 = expf(lrelu02(xs * Ss0 + xd * Sd0));
        float w1 = expf(lrelu02(xs * Ss1 + xd * Sd1));
        d0 += w0; n0 += w0 * xs;
        d1 += w1; n1 += w1 * xs;
    }
    d0 = lane64_sum(d0); n0 = lane64_sum(n0);
    d1 = lane64_sum(d1); n1 = lane64_sum(n1);
    if (lane == 0) {
        float w0 = expf(lrelu02(xd * (Ss0 + Sd0)));  // self-loop
        float w1 = expf(lrelu02(xd * (Ss1 + Sd1)));
        d0 += w0; n0 += w0 * xd;
        d1 += w1; n1 += w1 * xd;
        inv[(size_t)wid * 2 + 0] = n0 / (d0 + 1e-16f);
        inv[(size_t)wid * 2 + 1] = n1 / (d1 + 1e-16f);
    }
}

// ---- GAT1 epilogue + h2 = elu(z1) @ W2 + exp-tables for GAT2 attention ----
__global__ void k_node1(const float* __restrict__ inv, const float* __restrict__ W1,
                        const float* __restrict__ b1, const float* __restrict__ W2,
                        const float* __restrict__ as2w, const float* __restrict__ ad2w,
                        float* __restrict__ h2, float2* __restrict__ eab,
                        float* __restrict__ ad2) {
    __shared__ float sW1[HEADS * HDIM];
    __shared__ float sb1[HEADS * HDIM];
    __shared__ float sW2[HEADS * HDIM * (HDIM + 1)];
    __shared__ float sas[HDIM], sad[HDIM];
    __shared__ float z1s[NPB][HEADS * HDIM + 1];

    for (int i = threadIdx.x; i < HEADS * HDIM; i += blockDim.x) {
        sW1[i] = W1[i];
        sb1[i] = b1[i];
    }
    for (int i = threadIdx.x; i < HEADS * HDIM * HDIM; i += blockDim.x) {
        int k = i >> 5, c = i & 31;
        sW2[k * (HDIM + 1) + c] = W2[i];
    }
    for (int i = threadIdx.x; i < HDIM; i += blockDim.x) {
        sas[i] = as2w[i];
        sad[i] = ad2w[i];
    }
    __syncthreads();

    int ln = threadIdx.x >> 5;
    int c = threadIdx.x & 31;
    int tn = blockIdx.x * NPB + ln;
    if (tn >= TN) return;

    float inv0 = inv[(size_t)tn * 2 + 0];
    float inv1 = inv[(size_t)tn * 2 + 1];
    z1s[ln][c] = eluf(inv0 * sW1[c] + sb1[c]);
    z1s[ln][HDIM + c] = eluf(inv1 * sW1[HDIM + c] + sb1[HDIM + c]);
    __syncthreads();

    float acc = 0.f;
#pragma unroll
    for (int k = 0; k < HEADS * HDIM; ++k)
        acc += z1s[ln][k] * sW2[k * (HDIM + 1) + c];

    h2[(size_t)tn * HDIM + c] = acc;
    float s = lane32_sum(acc * sas[c]);
    float d = lane32_sum(acc * sad[c]);
    if (c == 0) {
        eab[tn] = make_float2(expf(s), expf(0.2f * s));  // exp(as2), exp(0.2*as2)
        ad2[tn] = d;
    }
}

// ---- GAT2 reduce: wave = 8 edges x 8 lanes x float4 channels; XCD-swizzled ----
__global__ void k_gat2red(const unsigned short* __restrict__ es, const int* __restrict__ row,
                          const float2* __restrict__ eab, const float* __restrict__ ad2,
                          const float* __restrict__ h2, const float* __restrict__ b2,
                          float* __restrict__ z2) {
    int b = blockIdx.x;
    int t = b & 7;            // XCD swizzle: all blocks on one XCD share one timestep
    int chunk = b >> 3;
    int wave = threadIdx.x >> 6;
    int lane = threadIdx.x & 63;
    int node = chunk * 4 + wave;          // exact: 5000 chunks * 4 waves = 20000
    int wid = t * N_NODES + node;
    int g = lane >> 3;                    // edge slot 0..7
    int l = lane & 7;                     // channel quad: channels 4l..4l+3

    int start = row[wid], end = row[wid + 1];
    float ad = ad2[wid];
    float Fa = expf(ad), Fb = expf(0.2f * ad), Et = expf(-ad);
    const float2* eabt = eab + (size_t)t * N_NODES;
    const float* h2t = h2 + (size_t)t * N_NODES * HDIM;

    float4 acc = make_float4(0.f, 0.f, 0.f, 0.f);
    float den = 0.f;
    for (int p = start + g; p < end; p += 8) {
        int s = es[p];
        float2 e = eabt[s];
        float w = (e.x > Et) ? e.x * Fa : e.y * Fb;
        float4 hv = *(const float4*)(h2t + (size_t)s * HDIM + 4 * l);
        acc.x += w * hv.x; acc.y += w * hv.y; acc.z += w * hv.z; acc.w += w * hv.w;
        den += w;
    }
#pragma unroll
    for (int off = 8; off < 64; off <<= 1) {
        acc.x += __shfl_xor(acc.x, off);
        acc.y += __shfl_xor(acc.y, off);
        acc.z += __shfl_xor(acc.z, off);
        acc.w += __shfl_xor(acc.w, off);
        den += __shfl_xor(den, off);
    }
    // self-loop (all lanes hold full sums post-reduction; harmless redundancy)
    float2 ed = eabt[node];
    float ws = (ed.x > Et) ? ed.x * Fa : ed.y * Fb;
    float4 hd = *(const float4*)(h2t + (size_t)node * HDIM + 4 * l);
    acc.x += ws * hd.x; acc.y += ws * hd.y; acc.z += ws * hd.z; acc.w += ws * hd.w;
    den += ws;

    if (g == 0) {
        float invd = 1.f / (den + 1e-16f);
        float4 o;
        o.x = eluf(acc.x * invd + b2[4 * l + 0]);
        o.y = eluf(acc.y * invd + b2[4 * l + 1]);
        o.z = eluf(acc.z * invd + b2[4 * l + 2]);
        o.w = eluf(acc.w * invd + b2[4 * l + 3]);
        *(float4*)(z2 + (size_t)wid * HDIM + 4 * l) = o;
    }
}

// ---- fused 8-step GRU + output projection ----
// 256 threads = 8 groups x 32 gate-channels; each group owns GNT=4 nodes.
// ALL accumulators are NAMED SCALARS (rule #20: runtime-indexed arrays go to
// scratch -> the 2.3 GB traffic of rounds 6/7). Weights in LDS, row stride 32,
// quad-XOR swizzle q^=row&7 (16B-aligned b128 reads, <=4-way conflict).
// z/h tiles row stride 32, float4 broadcast reads (conflict-free).
#define GRU_DECL(j) float air##j, aiz##j, ain##j, ahr##j, ahz##j, ahn##j, hr##j;
#define GRU_INIT(j) \
    air##j = br; aiz##j = bz; ain##j = bn; ahr##j = cr; ahz##j = cz; ahn##j = cn;
#define GRU_ACC(j) { \
    float4 zv = *(const float4*)&zls[(nb + j) * 32 + kq]; \
    float4 hv = *(const float4*)&hls[(nb + j) * 32 + kq]; \
    air##j = fmaf(wri.w, zv.w, fmaf(wri.z, zv.z, fmaf(wri.y, zv.y, fmaf(wri.x, zv.x, air##j)))); \
    aiz##j = fmaf(wzi.w, zv.w, fmaf(wzi.z, zv.z, fmaf(wzi.y, zv.y, fmaf(wzi.x, zv.x, aiz##j)))); \
    ain##j = fmaf(wni.w, zv.w, fmaf(wni.z, zv.z, fmaf(wni.y, zv.y, fmaf(wni.x, zv.x, ain##j)))); \
    ahr##j = fmaf(wrh.w, hv.w, fmaf(wrh.z, hv.z, fmaf(wrh.y, hv.y, fmaf(wrh.x, hv.x, ahr##j)))); \
    ahz##j = fmaf(wzh.w, hv.w, fmaf(wzh.z, hv.z, fmaf(wzh.y, hv.y, fmaf(wzh.x, hv.x, ahz##j)))); \
    ahn##j = fmaf(wnh.w, hv.w, fmaf(wnh.z, hv.z, fmaf(wnh.y, hv.y, fmaf(wnh.x, hv.x, ahn##j)))); }
#define GRU_FIN(j) { \
    float r = sigmoidf(air##j + ahr##j); \
    float z = sigmoidf(aiz##j + ahz##j); \
    float g = tanhf(ain##j + r * ahn##j); \
    hr##j = (1.f - z) * g + z * hr##j; \
    hls[(nb + j) * 32 + c] = hr##j; }

__global__ void __launch_bounds__(256, 2)
k_gru_all(const float* __restrict__ z2, const float* __restrict__ Wih,
          const float* __restrict__ Whh, const float* __restrict__ bih,
          const float* __restrict__ bhh, const float* __restrict__ Wout,
          const float* __restrict__ bout, float* __restrict__ out) {
    __shared__ float sWih[3 * HDIM * 32];  // swizzled rows
    __shared__ float sWhh[3 * HDIM * 32];
    __shared__ float sbih[3 * HDIM], sbhh[3 * HDIM], sWout[HDIM];
    __shared__ float hls[GNB * 32];
    __shared__ float zls[GNB * 32];

    for (int i = threadIdx.x; i < 3 * HDIM * HDIM; i += 256) {
        int r = i >> 5, cc = i & 31;
        int pos = r * 32 + ((((cc >> 2) ^ (r & 7)) << 2) | (cc & 3));
        sWih[pos] = Wih[i];
        sWhh[pos] = Whh[i];
    }
    for (int i = threadIdx.x; i < 3 * HDIM; i += 256) {
        sbih[i] = bih[i];
        sbhh[i] = bhh[i];
    }
    for (int i = threadIdx.x; i < HDIM; i += 256) sWout[i] = Wout[i];
    for (int i = threadIdx.x; i < GNB * 32; i += 256) hls[i] = 0.f;
    __syncthreads();

    const int c = threadIdx.x & 31;
    const int nb = (threadIdx.x >> 5) * GNT;   // group's node base (0..28)
    const int gbase = blockIdx.x * GNB;
    const int sw = c & 7;                       // row-XOR key (rows c,32+c,64+c share it)

    const float br = sbih[c], bz = sbih[HDIM + c], bn = sbih[2 * HDIM + c];
    const float cr = sbhh[c], cz = sbhh[HDIM + c], cn = sbhh[2 * HDIM + c];

    GRU_DECL(0) GRU_DECL(1) GRU_DECL(2) GRU_DECL(3)
    hr0 = hr1 = hr2 = hr3 = 0.f;

    for (int t = 0; t < T_STEPS; ++t) {
        // stage z2 tile (32 nodes x 32 ch): linear copy, one float4 per thread
        const float4* zsrc = (const float4*)(z2 + ((size_t)t * N_NODES + gbase) * HDIM);
        *(float4*)&zls[threadIdx.x * 4] = zsrc[threadIdx.x];
        __syncthreads();

        GRU_INIT(0) GRU_INIT(1) GRU_INIT(2) GRU_INIT(3)
#pragma unroll
        for (int q = 0; q < 8; ++q) {
            int qa = (q ^ sw) << 2;    // swizzled float-offset within row
            int kq = q << 2;           // true k position for z/h
            float4 wri = *(const float4*)&sWih[c * 32 + qa];
            float4 wzi = *(const float4*)&sWih[(HDIM + c) * 32 + qa];
            float4 wni = *(const float4*)&sWih[(2 * HDIM + c) * 32 + qa];
            float4 wrh = *(const float4*)&sWhh[c * 32 + qa];
            float4 wzh = *(const float4*)&sWhh[(HDIM + c) * 32 + qa];
            float4 wnh = *(const float4*)&sWhh[(2 * HDIM + c) * 32 + qa];
            GRU_ACC(0) GRU_ACC(1) GRU_ACC(2) GRU_ACC(3)
        }
        GRU_FIN(0) GRU_FIN(1) GRU_FIN(2) GRU_FIN(3)
        __syncthreads();  // zls reads done before next staging; hls same-wave ordered
    }

    float wo = sWout[c];
    float s0 = lane32_sum(hr0 * wo);
    float s1 = lane32_sum(hr1 * wo);
    float s2 = lane32_sum(hr2 * wo);
    float s3 = lane32_sum(hr3 * wo);
    if (c == 0) {
        float bo = bout[0];
        out[gbase + nb + 0] = s0 + bo;
        out[gbase + nb + 1] = s1 + bo;
        out[gbase + nb + 2] = s2 + bo;
        out[gbase + nb + 3] = s3 + bo;
    }
}

extern "C" void kernel_launch(void* const* d_in, const int* in_sizes, int n_in,
                              void* d_out, int out_size, void* d_ws, size_t ws_size,
                              hipStream_t stream) {
    const float* x      = (const float*)d_in[0];   // T*N
    const int* eidx     = (const int*)d_in[1];     // T*2*E
    const float* W1     = (const float*)d_in[2];
    const float* a_src1 = (const float*)d_in[3];
    const float* a_dst1 = (const float*)d_in[4];
    const float* b1     = (const float*)d_in[5];
    const float* W2     = (const float*)d_in[6];
    const float* a_src2 = (const float*)d_in[7];
    const float* a_dst2 = (const float*)d_in[8];
    const float* b2     = (const float*)d_in[9];
    const float* W_ih   = (const float*)d_in[10];
    const float* W_hh   = (const float*)d_in[11];
    const float* b_ih   = (const float*)d_in[12];
    const float* b_hh   = (const float*)d_in[13];
    const float* W_out  = (const float*)d_in[14];
    const float* b_out  = (const float*)d_in[15];
    float* out = (float*)d_out;

    char* base_ws = (char*)d_ws;
    size_t off = 0;
    auto alloc = [&](size_t bytes) {
        char* p = base_ws + off;
        off = (off + bytes + 15) & ~(size_t)15;
        return p;
    };
    int* cnt            = (int*)alloc((size_t)TN * 4);
    int* row            = (int*)alloc((size_t)(TN + 1) * 4);
    int* bsum           = (int*)alloc((size_t)SCAN_BLOCKS * 4);
    int* bpre           = (int*)alloc((size_t)SCAN_BLOCKS * 4);
    float* inv          = (float*)alloc((size_t)TN * 2 * 4);
    float* h2           = (float*)alloc((size_t)TN * HDIM * 4);
    float2* eab         = (float2*)alloc((size_t)TN * 8);
    float* ad2          = (float*)alloc((size_t)TN * 4);
    float* z2           = (float*)alloc((size_t)TN * HDIM * 4);
    float* S4           = (float*)alloc(16);
    unsigned short* es  = (unsigned short*)alloc((size_t)TE * 2);
    unsigned char* rank = (unsigned char*)alloc((size_t)TE);
    // hist/base alias h2's region: CSR build completes before k_node1 writes h2
    // (stream-ordered). Each is T*GB*NPAIR ints = 10.24 MB; h2 = 20.48 MB.
    int* hist = (int*)h2;
    int* bbase = hist + (size_t)T_STEPS * GB * NPAIR;

    const int B = 256;
    k_prep<<<1, 64, 0, stream>>>(W1, a_src1, a_dst1, S4);

    dim3 hgrid(GB, T_STEPS);
    k_hist<<<hgrid, 512, 0, stream>>>(eidx, hist, rank);
    k_blkpre<<<(T_STEPS * NPAIR + B - 1) / B, B, 0, stream>>>(hist, bbase, cnt);
    k_scan_a<<<SCAN_BLOCKS, B, 0, stream>>>(cnt, bsum);
    k_scan_b<<<1, B, 0, stream>>>(bsum, bpre);
    k_scan_c<<<SCAN_BLOCKS, B, 0, stream>>>(cnt, bpre, row);
    dim3 egrid((E_EDGES + B - 1) / B, T_STEPS);
    k_scatter<<<egrid, B, 0, stream>>>(eidx, rank, row, bbase, es);

    k_gat1red<<<TN / 4, B, 0, stream>>>(es, row, x, S4, inv);
    k_node1<<<TN / NPB, B, 0, stream>>>(inv, W1, b1, W2, a_src2, a_dst2, h2, eab, ad2);
    k_gat2red<<<TN / 4, B, 0, stream>>>(es, row, eab, ad2, h2, b2, z2);

    k_gru_all<<<N_NODES / GNB, B, 0, stream>>>(z2, W_ih, W_hh, b_ih, b_hh, W_out, b_out, out);
}

// Round 9
// 1016.676 us; speedup vs baseline: 1.0229x; 1.0229x over previous
//
#include <hip/hip_runtime.h>
#include <math.h>

#define N_NODES 20000
#define T_STEPS 8
#define E_EDGES 640000
#define TN (T_STEPS * N_NODES)   // 160000
#define TE (T_STEPS * E_EDGES)   // 5120000
#define HDIM 32
#define HEADS 2
#define NPB 8                    // nodes per block for lane-parallel node kernels
#define SCAN_BLOCKS 625          // TN / 256 exactly
#define GB 32                    // histogram blocks per timestep
#define CHUNK (E_EDGES / GB)     // 20000 edges per histogram block
#define NPAIR (N_NODES / 2)      // packed bins per timestep
#define GNT 4                    // GRU nodes per thread-group (named scalars only!)
#define GNB (8 * GNT)            // GRU nodes per block = 32 (625 blocks exactly)

__device__ __forceinline__ float lrelu02(float v) { return v > 0.f ? v : 0.2f * v; }
__device__ __forceinline__ float eluf(float v) { return v > 0.f ? v : expm1f(v); }
__device__ __forceinline__ float sigmoidf(float v) { return 1.f / (1.f + expf(-v)); }

__device__ __forceinline__ float lane32_sum(float v) {
    v += __shfl_xor(v, 16);
    v += __shfl_xor(v, 8);
    v += __shfl_xor(v, 4);
    v += __shfl_xor(v, 2);
    v += __shfl_xor(v, 1);
    return v;
}
__device__ __forceinline__ float lane64_sum(float v) {
    v += __shfl_xor(v, 32);
    return lane32_sum(v);
}

// ---- precompute S_s1[2], S_d1[2] (rank-1 GAT1 attention constants) ----
__global__ void k_prep(const float* __restrict__ W1, const float* __restrict__ as1,
                       const float* __restrict__ ad1, float* __restrict__ S4) {
    if (threadIdx.x == 0 && blockIdx.x == 0) {
        for (int hd = 0; hd < HEADS; ++hd) {
            float ss = 0.f, sd = 0.f;
            for (int c = 0; c < HDIM; ++c) {
                ss += W1[hd * HDIM + c] * as1[hd * HDIM + c];
                sd += W1[hd * HDIM + c] * ad1[hd * HDIM + c];
            }
            S4[hd] = ss;
            S4[HEADS + hd] = sd;
        }
    }
}

// ---- pass A: per-block LDS histogram + local rank (NO global atomics) ----
__global__ void k_hist(const int* __restrict__ ei, int* __restrict__ hist,
                       unsigned char* __restrict__ rank) {
    __shared__ int lh[NPAIR];  // 40 KB
    int t = blockIdx.y, b = blockIdx.x;
    for (int i = threadIdx.x; i < NPAIR; i += blockDim.x) lh[i] = 0;
    __syncthreads();
    const int* dstp = ei + (size_t)t * 2 * E_EDGES + E_EDGES + b * CHUNK;
    unsigned char* rk = rank + (size_t)t * E_EDGES + b * CHUNK;
    for (int j = threadIdx.x; j < CHUNK; j += blockDim.x) {
        int dst = dstp[j];
        int old = atomicAdd(&lh[dst >> 1], (dst & 1) ? 65536 : 1);
        rk[j] = (unsigned char)((old >> (16 * (dst & 1))) & 0xffff);
    }
    __syncthreads();
    int* hp = hist + ((size_t)t * GB + b) * NPAIR;
    for (int i = threadIdx.x; i < NPAIR; i += blockDim.x) hp[i] = lh[i];
}

// ---- pass B: per-(t,dst) prefix over blocks -> base (packed) + totals ----
__global__ void k_blkpre(const int* __restrict__ hist, int* __restrict__ base,
                         int* __restrict__ cnt) {
    int i = blockIdx.x * blockDim.x + threadIdx.x;  // (t, pair)
    if (i >= T_STEPS * NPAIR) return;
    int t = i / NPAIR, pr = i % NPAIR;
    int a0 = 0, a1 = 0;
    for (int b = 0; b < GB; ++b) {
        size_t idx = ((size_t)t * GB + b) * NPAIR + pr;
        int v = hist[idx];
        base[idx] = a0 | (a1 << 16);
        a0 += v & 0xffff;
        a1 += (v >> 16) & 0xffff;
    }
    cnt[t * N_NODES + 2 * pr] = a0;
    cnt[t * N_NODES + 2 * pr + 1] = a1;
}

// ---- scan (exclusive) over cnt[TN] -> row[TN+1] ----
__global__ void k_scan_a(const int* __restrict__ cnt, int* __restrict__ bsum) {
    __shared__ int s[256];
    int i = blockIdx.x * 256 + threadIdx.x;
    s[threadIdx.x] = (i < TN) ? cnt[i] : 0;
    __syncthreads();
    for (int off = 128; off > 0; off >>= 1) {
        if (threadIdx.x < off) s[threadIdx.x] += s[threadIdx.x + off];
        __syncthreads();
    }
    if (threadIdx.x == 0) bsum[blockIdx.x] = s[0];
}

__global__ void k_scan_b(const int* __restrict__ bsum, int* __restrict__ bpre) {
    __shared__ int s[256];
    __shared__ int carry;
    if (threadIdx.x == 0) carry = 0;
    __syncthreads();
    for (int base = 0; base < SCAN_BLOCKS; base += 256) {
        int i = base + threadIdx.x;
        int v = (i < SCAN_BLOCKS) ? bsum[i] : 0;
        s[threadIdx.x] = v;
        __syncthreads();
        for (int off = 1; off < 256; off <<= 1) {
            int add = (threadIdx.x >= off) ? s[threadIdx.x - off] : 0;
            __syncthreads();
            s[threadIdx.x] += add;
            __syncthreads();
        }
        if (i < SCAN_BLOCKS) bpre[i] = carry + s[threadIdx.x] - v;  // exclusive
        __syncthreads();
        if (threadIdx.x == 0) carry += s[255];
        __syncthreads();
    }
}

__global__ void k_scan_c(const int* __restrict__ cnt, const int* __restrict__ bpre,
                         int* __restrict__ row) {
    __shared__ int s[256];
    int i = blockIdx.x * 256 + threadIdx.x;
    int v = (i < TN) ? cnt[i] : 0;
    s[threadIdx.x] = v;
    __syncthreads();
    for (int off = 1; off < 256; off <<= 1) {
        int add = (threadIdx.x >= off) ? s[threadIdx.x - off] : 0;
        __syncthreads();
        s[threadIdx.x] += add;
        __syncthreads();
    }
    if (i < TN) row[i] = bpre[blockIdx.x] + s[threadIdx.x] - v;
    if (blockIdx.x == 0 && threadIdx.x == 0) row[TN] = TE;
}

// ---- pass C: scatter src into dst-sorted order (plain stores) ----
__global__ void k_scatter(const int* __restrict__ ei, const unsigned char* __restrict__ rank,
                          const int* __restrict__ row, const int* __restrict__ base,
                          unsigned short* __restrict__ es) {
    int j = blockIdx.x * blockDim.x + threadIdx.x;
    int t = blockIdx.y;
    if (j >= E_EDGES) return;
    size_t eb = (size_t)t * 2 * E_EDGES;
    int src = ei[eb + j];
    int dst = ei[eb + E_EDGES + j];
    int b = j / CHUNK;
    int bs = base[((size_t)t * GB + b) * NPAIR + (dst >> 1)];
    bs = (bs >> (16 * (dst & 1))) & 0xffff;
    int r = rank[(size_t)t * E_EDGES + j];
    es[row[t * N_NODES + dst] + bs + r] = (unsigned short)src;
}

// ---- GAT1 reduce: one wave per (t,dst), register accumulation ----
__global__ void k_gat1red(const unsigned short* __restrict__ es, const int* __restrict__ row,
                          const float* __restrict__ x, const float* __restrict__ S4,
                          float* __restrict__ inv) {
    int wid = (blockIdx.x * blockDim.x + threadIdx.x) >> 6;  // (t,dst) bin
    int lane = threadIdx.x & 63;
    if (wid >= TN) return;
    int t = wid / N_NODES;
    int start = row[wid], end = row[wid + 1];
    float Ss0 = S4[0], Ss1 = S4[1], Sd0 = S4[2], Sd1 = S4[3];
    float xd = x[wid];
    float d0 = 0.f, n0 = 0.f, d1 = 0.f, n1 = 0.f;
    const float* xt = x + (size_t)t * N_NODES;
    for (int p = start + lane; p < end; p += 64) {
        float xs = xt[es[p]];
        float w0 = expf(lrelu02(xs * Ss0 + xd * Sd0));
        float w1 = expf(lrelu02(xs * Ss1 + xd * Sd1));
        d0 += w0; n0 += w0 * xs;
        d1 += w1; n1 += w1 * xs;
    }
    d0 = lane64_sum(d0); n0 = lane64_sum(n0);
    d1 = lane64_sum(d1); n1 = lane64_sum(n1);
    if (lane == 0) {
        float w0 = expf(lrelu02(xd * (Ss0 + Sd0)));  // self-loop
        float w1 = expf(lrelu02(xd * (Ss1 + Sd1)));
        d0 += w0; n0 += w0 * xd;
        d1 += w1; n1 += w1 * xd;
        inv[(size_t)wid * 2 + 0] = n0 / (d0 + 1e-16f);
        inv[(size_t)wid * 2 + 1] = n1 / (d1 + 1e-16f);
    }
}

// ---- GAT1 epilogue + h2 = elu(z1) @ W2 + exp-tables for GAT2 attention ----
__global__ void k_node1(const float* __restrict__ inv, const float* __restrict__ W1,
                        const float* __restrict__ b1, const float* __restrict__ W2,
                        const float* __restrict__ as2w, const float* __restrict__ ad2w,
                        float* __restrict__ h2, float2* __restrict__ eab,
                        float* __restrict__ ad2) {
    __shared__ float sW1[HEADS * HDIM];
    __shared__ float sb1[HEADS * HDIM];
    __shared__ float sW2[HEADS * HDIM * (HDIM + 1)];
    __shared__ float sas[HDIM], sad[HDIM];
    __shared__ float z1s[NPB][HEADS * HDIM + 1];

    for (int i = threadIdx.x; i < HEADS * HDIM; i += blockDim.x) {
        sW1[i] = W1[i];
        sb1[i] = b1[i];
    }
    for (int i = threadIdx.x; i < HEADS * HDIM * HDIM; i += blockDim.x) {
        int k = i >> 5, c = i & 31;
        sW2[k * (HDIM + 1) + c] = W2[i];
    }
    for (int i = threadIdx.x; i < HDIM; i += blockDim.x) {
        sas[i] = as2w[i];
        sad[i] = ad2w[i];
    }
    __syncthreads();

    int ln = threadIdx.x >> 5;
    int c = threadIdx.x & 31;
    int tn = blockIdx.x * NPB + ln;
    if (tn >= TN) return;

    float inv0 = inv[(size_t)tn * 2 + 0];
    float inv1 = inv[(size_t)tn * 2 + 1];
    z1s[ln][c] = eluf(inv0 * sW1[c] + sb1[c]);
    z1s[ln][HDIM + c] = eluf(inv1 * sW1[HDIM + c] + sb1[HDIM + c]);
    __syncthreads();

    float acc = 0.f;
#pragma unroll
    for (int k = 0; k < HEADS * HDIM; ++k)
        acc += z1s[ln][k] * sW2[k * (HDIM + 1) + c];

    h2[(size_t)tn * HDIM + c] = acc;
    float s = lane32_sum(acc * sas[c]);
    float d = lane32_sum(acc * sad[c]);
    if (c == 0) {
        eab[tn] = make_float2(expf(s), expf(0.2f * s));  // exp(as2), exp(0.2*as2)
        ad2[tn] = d;
    }
}

// ---- GAT2 reduce: wave = 8 edges x 8 lanes x float4 channels; XCD-swizzled ----
__global__ void k_gat2red(const unsigned short* __restrict__ es, const int* __restrict__ row,
                          const float2* __restrict__ eab, const float* __restrict__ ad2,
                          const float* __restrict__ h2, const float* __restrict__ b2,
                          float* __restrict__ z2) {
    int b = blockIdx.x;
    int t = b & 7;            // XCD swizzle: all blocks on one XCD share one timestep
    int chunk = b >> 3;
    int wave = threadIdx.x >> 6;
    int lane = threadIdx.x & 63;
    int node = chunk * 4 + wave;          // exact: 5000 chunks * 4 waves = 20000
    int wid = t * N_NODES + node;
    int g = lane >> 3;                    // edge slot 0..7
    int l = lane & 7;                     // channel quad: channels 4l..4l+3

    int start = row[wid], end = row[wid + 1];
    float ad = ad2[wid];
    float Fa = expf(ad), Fb = expf(0.2f * ad), Et = expf(-ad);
    const float2* eabt = eab + (size_t)t * N_NODES;
    const float* h2t = h2 + (size_t)t * N_NODES * HDIM;

    float4 acc = make_float4(0.f, 0.f, 0.f, 0.f);
    float den = 0.f;
    for (int p = start + g; p < end; p += 8) {
        int s = es[p];
        float2 e = eabt[s];
        float w = (e.x > Et) ? e.x * Fa : e.y * Fb;
        float4 hv = *(const float4*)(h2t + (size_t)s * HDIM + 4 * l);
        acc.x += w * hv.x; acc.y += w * hv.y; acc.z += w * hv.z; acc.w += w * hv.w;
        den += w;
    }
#pragma unroll
    for (int off = 8; off < 64; off <<= 1) {
        acc.x += __shfl_xor(acc.x, off);
        acc.y += __shfl_xor(acc.y, off);
        acc.z += __shfl_xor(acc.z, off);
        acc.w += __shfl_xor(acc.w, off);
        den += __shfl_xor(den, off);
    }
    // self-loop (all lanes hold full sums post-reduction; harmless redundancy)
    float2 ed = eabt[node];
    float ws = (ed.x > Et) ? ed.x * Fa : ed.y * Fb;
    float4 hd = *(const float4*)(h2t + (size_t)node * HDIM + 4 * l);
    acc.x += ws * hd.x; acc.y += ws * hd.y; acc.z += ws * hd.z; acc.w += ws * hd.w;
    den += ws;

    if (g == 0) {
        float invd = 1.f / (den + 1e-16f);
        float4 o;
        o.x = eluf(acc.x * invd + b2[4 * l + 0]);
        o.y = eluf(acc.y * invd + b2[4 * l + 1]);
        o.z = eluf(acc.z * invd + b2[4 * l + 2]);
        o.w = eluf(acc.w * invd + b2[4 * l + 3]);
        *(float4*)(z2 + (size_t)wid * HDIM + 4 * l) = o;
    }
}

// ---- fused 8-step GRU + output projection ----
// 256 threads = 8 groups x 32 gate-channels; each group owns GNT=4 nodes.
// ALL accumulators are NAMED SCALARS (rule #20: runtime-indexed arrays go to
// scratch -> the 2.3 GB traffic of rounds 6/7). Weights in LDS, row stride 32,
// quad-XOR swizzle q^=row&7 (16B-aligned b128 reads, <=4-way conflict).
// z/h tiles row stride 32, float4 broadcast reads (conflict-free).
#define GRU_DECL(j) float air##j, aiz##j, ain##j, ahr##j, ahz##j, ahn##j, hr##j;
#define GRU_INIT(j) \
    air##j = br; aiz##j = bz; ain##j = bn; ahr##j = cr; ahz##j = cz; ahn##j = cn;
#define GRU_ACC(j) { \
    float4 zv = *(const float4*)&zls[(nb + j) * 32 + kq]; \
    float4 hv = *(const float4*)&hls[(nb + j) * 32 + kq]; \
    air##j = fmaf(wri.w, zv.w, fmaf(wri.z, zv.z, fmaf(wri.y, zv.y, fmaf(wri.x, zv.x, air##j)))); \
    aiz##j = fmaf(wzi.w, zv.w, fmaf(wzi.z, zv.z, fmaf(wzi.y, zv.y, fmaf(wzi.x, zv.x, aiz##j)))); \
    ain##j = fmaf(wni.w, zv.w, fmaf(wni.z, zv.z, fmaf(wni.y, zv.y, fmaf(wni.x, zv.x, ain##j)))); \
    ahr##j = fmaf(wrh.w, hv.w, fmaf(wrh.z, hv.z, fmaf(wrh.y, hv.y, fmaf(wrh.x, hv.x, ahr##j)))); \
    ahz##j = fmaf(wzh.w, hv.w, fmaf(wzh.z, hv.z, fmaf(wzh.y, hv.y, fmaf(wzh.x, hv.x, ahz##j)))); \
    ahn##j = fmaf(wnh.w, hv.w, fmaf(wnh.z, hv.z, fmaf(wnh.y, hv.y, fmaf(wnh.x, hv.x, ahn##j)))); }
#define GRU_FIN(j) { \
    float r = sigmoidf(air##j + ahr##j); \
    float z = sigmoidf(aiz##j + ahz##j); \
    float g = tanhf(ain##j + r * ahn##j); \
    hr##j = (1.f - z) * g + z * hr##j; \
    hls[(nb + j) * 32 + c] = hr##j; }

__global__ void __launch_bounds__(256, 2)
k_gru_all(const float* __restrict__ z2, const float* __restrict__ Wih,
          const float* __restrict__ Whh, const float* __restrict__ bih,
          const float* __restrict__ bhh, const float* __restrict__ Wout,
          const float* __restrict__ bout, float* __restrict__ out) {
    __shared__ float sWih[3 * HDIM * 32];  // swizzled rows
    __shared__ float sWhh[3 * HDIM * 32];
    __shared__ float sbih[3 * HDIM], sbhh[3 * HDIM], sWout[HDIM];
    __shared__ float hls[GNB * 32];
    __shared__ float zls[GNB * 32];

    for (int i = threadIdx.x; i < 3 * HDIM * HDIM; i += 256) {
        int r = i >> 5, cc = i & 31;
        int pos = r * 32 + ((((cc >> 2) ^ (r & 7)) << 2) | (cc & 3));
        sWih[pos] = Wih[i];
        sWhh[pos] = Whh[i];
    }
    for (int i = threadIdx.x; i < 3 * HDIM; i += 256) {
        sbih[i] = bih[i];
        sbhh[i] = bhh[i];
    }
    for (int i = threadIdx.x; i < HDIM; i += 256) sWout[i] = Wout[i];
    for (int i = threadIdx.x; i < GNB * 32; i += 256) hls[i] = 0.f;
    __syncthreads();

    const int c = threadIdx.x & 31;
    const int nb = (threadIdx.x >> 5) * GNT;   // group's node base (0..28)
    const int gbase = blockIdx.x * GNB;
    const int sw = c & 7;                       // row-XOR key (rows c,32+c,64+c share it)

    const float br = sbih[c], bz = sbih[HDIM + c], bn = sbih[2 * HDIM + c];
    const float cr = sbhh[c], cz = sbhh[HDIM + c], cn = sbhh[2 * HDIM + c];

    GRU_DECL(0) GRU_DECL(1) GRU_DECL(2) GRU_DECL(3)
    hr0 = hr1 = hr2 = hr3 = 0.f;

    for (int t = 0; t < T_STEPS; ++t) {
        // stage z2 tile (32 nodes x 32 ch): linear copy, one float4 per thread
        const float4* zsrc = (const float4*)(z2 + ((size_t)t * N_NODES + gbase) * HDIM);
        *(float4*)&zls[threadIdx.x * 4] = zsrc[threadIdx.x];
        __syncthreads();

        GRU_INIT(0) GRU_INIT(1) GRU_INIT(2) GRU_INIT(3)
#pragma unroll
        for (int q = 0; q < 8; ++q) {
            int qa = (q ^ sw) << 2;    // swizzled float-offset within row
            int kq = q << 2;           // true k position for z/h
            float4 wri = *(const float4*)&sWih[c * 32 + qa];
            float4 wzi = *(const float4*)&sWih[(HDIM + c) * 32 + qa];
            float4 wni = *(const float4*)&sWih[(2 * HDIM + c) * 32 + qa];
            float4 wrh = *(const float4*)&sWhh[c * 32 + qa];
            float4 wzh = *(const float4*)&sWhh[(HDIM + c) * 32 + qa];
            float4 wnh = *(const float4*)&sWhh[(2 * HDIM + c) * 32 + qa];
            GRU_ACC(0) GRU_ACC(1) GRU_ACC(2) GRU_ACC(3)
        }
        GRU_FIN(0) GRU_FIN(1) GRU_FIN(2) GRU_FIN(3)
        __syncthreads();  // zls reads done before next staging; hls same-wave ordered
    }

    float wo = sWout[c];
    float s0 = lane32_sum(hr0 * wo);
    float s1 = lane32_sum(hr1 * wo);
    float s2 = lane32_sum(hr2 * wo);
    float s3 = lane32_sum(hr3 * wo);
    if (c == 0) {
        float bo = bout[0];
        out[gbase + nb + 0] = s0 + bo;
        out[gbase + nb + 1] = s1 + bo;
        out[gbase + nb + 2] = s2 + bo;
        out[gbase + nb + 3] = s3 + bo;
    }
}

extern "C" void kernel_launch(void* const* d_in, const int* in_sizes, int n_in,
                              void* d_out, int out_size, void* d_ws, size_t ws_size,
                              hipStream_t stream) {
    const float* x      = (const float*)d_in[0];   // T*N
    const int* eidx     = (const int*)d_in[1];     // T*2*E
    const float* W1     = (const float*)d_in[2];
    const float* a_src1 = (const float*)d_in[3];
    const float* a_dst1 = (const float*)d_in[4];
    const float* b1     = (const float*)d_in[5];
    const float* W2     = (const float*)d_in[6];
    const float* a_src2 = (const float*)d_in[7];
    const float* a_dst2 = (const float*)d_in[8];
    const float* b2     = (const float*)d_in[9];
    const float* W_ih   = (const float*)d_in[10];
    const float* W_hh   = (const float*)d_in[11];
    const float* b_ih   = (const float*)d_in[12];
    const float* b_hh   = (const float*)d_in[13];
    const float* W_out  = (const float*)d_in[14];
    const float* b_out  = (const float*)d_in[15];
    float* out = (float*)d_out;

    char* base_ws = (char*)d_ws;
    size_t off = 0;
    auto alloc = [&](size_t bytes) {
        char* p = base_ws + off;
        off = (off + bytes + 15) & ~(size_t)15;
        return p;
    };
    int* cnt            = (int*)alloc((size_t)TN * 4);
    int* row            = (int*)alloc((size_t)(TN + 1) * 4);
    int* bsum           = (int*)alloc((size_t)SCAN_BLOCKS * 4);
    int* bpre           = (int*)alloc((size_t)SCAN_BLOCKS * 4);
    float* inv          = (float*)alloc((size_t)TN * 2 * 4);
    float* h2           = (float*)alloc((size_t)TN * HDIM * 4);
    float2* eab         = (float2*)alloc((size_t)TN * 8);
    float* ad2          = (float*)alloc((size_t)TN * 4);
    float* z2           = (float*)alloc((size_t)TN * HDIM * 4);
    float* S4           = (float*)alloc(16);
    unsigned short* es  = (unsigned short*)alloc((size_t)TE * 2);
    unsigned char* rank = (unsigned char*)alloc((size_t)TE);
    // hist/base alias h2's region: CSR build completes before k_node1 writes h2
    // (stream-ordered). Each is T*GB*NPAIR ints = 10.24 MB; h2 = 20.48 MB.
    int* hist = (int*)h2;
    int* bbase = hist + (size_t)T_STEPS * GB * NPAIR;

    const int B = 256;
    k_prep<<<1, 64, 0, stream>>>(W1, a_src1, a_dst1, S4);

    dim3 hgrid(GB, T_STEPS);
    k_hist<<<hgrid, 512, 0, stream>>>(eidx, hist, rank);
    k_blkpre<<<(T_STEPS * NPAIR + B - 1) / B, B, 0, stream>>>(hist, bbase, cnt);
    k_scan_a<<<SCAN_BLOCKS, B, 0, stream>>>(cnt, bsum);
    k_scan_b<<<1, B, 0, stream>>>(bsum, bpre);
    k_scan_c<<<SCAN_BLOCKS, B, 0, stream>>>(cnt, bpre, row);
    dim3 egrid((E_EDGES + B - 1) / B, T_STEPS);
    k_scatter<<<egrid, B, 0, stream>>>(eidx, rank, row, bbase, es);

    k_gat1red<<<TN / 4, B, 0, stream>>>(es, row, x, S4, inv);
    k_node1<<<TN / NPB, B, 0, stream>>>(inv, W1, b1, W2, a_src2, a_dst2, h2, eab, ad2);
    k_gat2red<<<TN / 4, B, 0, stream>>>(es, row, eab, ad2, h2, b2, z2);

    k_gru_all<<<N_NODES / GNB, B, 0, stream>>>(z2, W_ih, W_hh, b_ih, b_hh, W_out, b_out, out);
}

// Round 10
// 384.958 us; speedup vs baseline: 2.7015x; 2.6410x over previous
//
#include <hip/hip_runtime.h>
#include <math.h>

#define N_NODES 20000
#define T_STEPS 8
#define E_EDGES 640000
#define TN (T_STEPS * N_NODES)   // 160000
#define TE (T_STEPS * E_EDGES)   // 5120000
#define HDIM 32
#define HEADS 2
#define NPB 8                    // nodes per block for lane-parallel node kernels
#define SCAN_BLOCKS 625          // TN / 256 exactly
#define GB 32                    // histogram blocks per timestep
#define CHUNK (E_EDGES / GB)     // 20000 edges per histogram block
#define NPAIR (N_NODES / 2)      // packed bins per timestep
#define GNT 4                    // GRU nodes per thread-group (named scalars only!)
#define GNB (8 * GNT)            // GRU nodes per block = 32 (625 blocks exactly)

__device__ __forceinline__ float lrelu02(float v) { return v > 0.f ? v : 0.2f * v; }
__device__ __forceinline__ float eluf(float v) { return v > 0.f ? v : expm1f(v); }
__device__ __forceinline__ float sigmoidf(float v) { return 1.f / (1.f + expf(-v)); }

__device__ __forceinline__ float lane32_sum(float v) {
    v += __shfl_xor(v, 16);
    v += __shfl_xor(v, 8);
    v += __shfl_xor(v, 4);
    v += __shfl_xor(v, 2);
    v += __shfl_xor(v, 1);
    return v;
}
__device__ __forceinline__ float lane64_sum(float v) {
    v += __shfl_xor(v, 32);
    return lane32_sum(v);
}

// ---- precompute S_s1[2], S_d1[2] (rank-1 GAT1 attention constants) ----
__global__ void k_prep(const float* __restrict__ W1, const float* __restrict__ as1,
                       const float* __restrict__ ad1, float* __restrict__ S4) {
    if (threadIdx.x == 0 && blockIdx.x == 0) {
        for (int hd = 0; hd < HEADS; ++hd) {
            float ss = 0.f, sd = 0.f;
            for (int c = 0; c < HDIM; ++c) {
                ss += W1[hd * HDIM + c] * as1[hd * HDIM + c];
                sd += W1[hd * HDIM + c] * ad1[hd * HDIM + c];
            }
            S4[hd] = ss;
            S4[HEADS + hd] = sd;
        }
    }
}

// ---- pass A: per-block LDS histogram + local rank (NO global atomics) ----
__global__ void k_hist(const int* __restrict__ ei, int* __restrict__ hist,
                       unsigned char* __restrict__ rank) {
    __shared__ int lh[NPAIR];  // 40 KB
    int t = blockIdx.y, b = blockIdx.x;
    for (int i = threadIdx.x; i < NPAIR; i += blockDim.x) lh[i] = 0;
    __syncthreads();
    const int* dstp = ei + (size_t)t * 2 * E_EDGES + E_EDGES + b * CHUNK;
    unsigned char* rk = rank + (size_t)t * E_EDGES + b * CHUNK;
    for (int j = threadIdx.x; j < CHUNK; j += blockDim.x) {
        int dst = dstp[j];
        int old = atomicAdd(&lh[dst >> 1], (dst & 1) ? 65536 : 1);
        rk[j] = (unsigned char)((old >> (16 * (dst & 1))) & 0xffff);
    }
    __syncthreads();
    int* hp = hist + ((size_t)t * GB + b) * NPAIR;
    for (int i = threadIdx.x; i < NPAIR; i += blockDim.x) hp[i] = lh[i];
}

// ---- pass B: per-(t,dst) prefix over blocks -> base (packed) + totals ----
__global__ void k_blkpre(const int* __restrict__ hist, int* __restrict__ base,
                         int* __restrict__ cnt) {
    int i = blockIdx.x * blockDim.x + threadIdx.x;  // (t, pair)
    if (i >= T_STEPS * NPAIR) return;
    int t = i / NPAIR, pr = i % NPAIR;
    int a0 = 0, a1 = 0;
    for (int b = 0; b < GB; ++b) {
        size_t idx = ((size_t)t * GB + b) * NPAIR + pr;
        int v = hist[idx];
        base[idx] = a0 | (a1 << 16);
        a0 += v & 0xffff;
        a1 += (v >> 16) & 0xffff;
    }
    cnt[t * N_NODES + 2 * pr] = a0;
    cnt[t * N_NODES + 2 * pr + 1] = a1;
}

// ---- scan (exclusive) over cnt[TN] -> row[TN+1] ----
__global__ void k_scan_a(const int* __restrict__ cnt, int* __restrict__ bsum) {
    __shared__ int s[256];
    int i = blockIdx.x * 256 + threadIdx.x;
    s[threadIdx.x] = (i < TN) ? cnt[i] : 0;
    __syncthreads();
    for (int off = 128; off > 0; off >>= 1) {
        if (threadIdx.x < off) s[threadIdx.x] += s[threadIdx.x + off];
        __syncthreads();
    }
    if (threadIdx.x == 0) bsum[blockIdx.x] = s[0];
}

__global__ void k_scan_b(const int* __restrict__ bsum, int* __restrict__ bpre) {
    __shared__ int s[256];
    __shared__ int carry;
    if (threadIdx.x == 0) carry = 0;
    __syncthreads();
    for (int base = 0; base < SCAN_BLOCKS; base += 256) {
        int i = base + threadIdx.x;
        int v = (i < SCAN_BLOCKS) ? bsum[i] : 0;
        s[threadIdx.x] = v;
        __syncthreads();
        for (int off = 1; off < 256; off <<= 1) {
            int add = (threadIdx.x >= off) ? s[threadIdx.x - off] : 0;
            __syncthreads();
            s[threadIdx.x] += add;
            __syncthreads();
        }
        if (i < SCAN_BLOCKS) bpre[i] = carry + s[threadIdx.x] - v;  // exclusive
        __syncthreads();
        if (threadIdx.x == 0) carry += s[255];
        __syncthreads();
    }
}

__global__ void k_scan_c(const int* __restrict__ cnt, const int* __restrict__ bpre,
                         int* __restrict__ row) {
    __shared__ int s[256];
    int i = blockIdx.x * 256 + threadIdx.x;
    int v = (i < TN) ? cnt[i] : 0;
    s[threadIdx.x] = v;
    __syncthreads();
    for (int off = 1; off < 256; off <<= 1) {
        int add = (threadIdx.x >= off) ? s[threadIdx.x - off] : 0;
        __syncthreads();
        s[threadIdx.x] += add;
        __syncthreads();
    }
    if (i < TN) row[i] = bpre[blockIdx.x] + s[threadIdx.x] - v;
    if (blockIdx.x == 0 && threadIdx.x == 0) row[TN] = TE;
}

// ---- pass C: scatter src into dst-sorted order (plain stores) ----
__global__ void k_scatter(const int* __restrict__ ei, const unsigned char* __restrict__ rank,
                          const int* __restrict__ row, const int* __restrict__ base,
                          unsigned short* __restrict__ es) {
    int j = blockIdx.x * blockDim.x + threadIdx.x;
    int t = blockIdx.y;
    if (j >= E_EDGES) return;
    size_t eb = (size_t)t * 2 * E_EDGES;
    int src = ei[eb + j];
    int dst = ei[eb + E_EDGES + j];
    int b = j / CHUNK;
    int bs = base[((size_t)t * GB + b) * NPAIR + (dst >> 1)];
    bs = (bs >> (16 * (dst & 1))) & 0xffff;
    int r = rank[(size_t)t * E_EDGES + j];
    es[row[t * N_NODES + dst] + bs + r] = (unsigned short)src;
}

// ---- GAT1 reduce: one wave per (t,dst), register accumulation ----
__global__ void k_gat1red(const unsigned short* __restrict__ es, const int* __restrict__ row,
                          const float* __restrict__ x, const float* __restrict__ S4,
                          float* __restrict__ inv) {
    int wid = (blockIdx.x * blockDim.x + threadIdx.x) >> 6;  // (t,dst) bin
    int lane = threadIdx.x & 63;
    if (wid >= TN) return;
    int t = wid / N_NODES;
    int start = row[wid], end = row[wid + 1];
    float Ss0 = S4[0], Ss1 = S4[1], Sd0 = S4[2], Sd1 = S4[3];
    float xd = x[wid];
    float d0 = 0.f, n0 = 0.f, d1 = 0.f, n1 = 0.f;
    const float* xt = x + (size_t)t * N_NODES;
    for (int p = start + lane; p < end; p += 64) {
        float xs = xt[es[p]];
        float w0 = expf(lrelu02(xs * Ss0 + xd * Sd0));
        float w1 = expf(lrelu02(xs * Ss1 + xd * Sd1));
        d0 += w0; n0 += w0 * xs;
        d1 += w1; n1 += w1 * xs;
    }
    d0 = lane64_sum(d0); n0 = lane64_sum(n0);
    d1 = lane64_sum(d1); n1 = lane64_sum(n1);
    if (lane == 0) {
        float w0 = expf(lrelu02(xd * (Ss0 + Sd0)));  // self-loop
        float w1 = expf(lrelu02(xd * (Ss1 + Sd1)));
        d0 += w0; n0 += w0 * xd;
        d1 += w1; n1 += w1 * xd;
        inv[(size_t)wid * 2 + 0] = n0 / (d0 + 1e-16f);
        inv[(size_t)wid * 2 + 1] = n1 / (d1 + 1e-16f);
    }
}

// ---- GAT1 epilogue + h2 = elu(z1) @ W2 + exp-tables for GAT2 attention ----
__global__ void k_node1(const float* __restrict__ inv, const float* __restrict__ W1,
                        const float* __restrict__ b1, const float* __restrict__ W2,
                        const float* __restrict__ as2w, const float* __restrict__ ad2w,
                        float* __restrict__ h2, float2* __restrict__ eab,
                        float* __restrict__ ad2) {
    __shared__ float sW1[HEADS * HDIM];
    __shared__ float sb1[HEADS * HDIM];
    __shared__ float sW2[HEADS * HDIM * (HDIM + 1)];
    __shared__ float sas[HDIM], sad[HDIM];
    __shared__ float z1s[NPB][HEADS * HDIM + 1];

    for (int i = threadIdx.x; i < HEADS * HDIM; i += blockDim.x) {
        sW1[i] = W1[i];
        sb1[i] = b1[i];
    }
    for (int i = threadIdx.x; i < HEADS * HDIM * HDIM; i += blockDim.x) {
        int k = i >> 5, c = i & 31;
        sW2[k * (HDIM + 1) + c] = W2[i];
    }
    for (int i = threadIdx.x; i < HDIM; i += blockDim.x) {
        sas[i] = as2w[i];
        sad[i] = ad2w[i];
    }
    __syncthreads();

    int ln = threadIdx.x >> 5;
    int c = threadIdx.x & 31;
    int tn = blockIdx.x * NPB + ln;
    if (tn >= TN) return;

    float inv0 = inv[(size_t)tn * 2 + 0];
    float inv1 = inv[(size_t)tn * 2 + 1];
    z1s[ln][c] = eluf(inv0 * sW1[c] + sb1[c]);
    z1s[ln][HDIM + c] = eluf(inv1 * sW1[HDIM + c] + sb1[HDIM + c]);
    __syncthreads();

    float acc = 0.f;
#pragma unroll
    for (int k = 0; k < HEADS * HDIM; ++k)
        acc += z1s[ln][k] * sW2[k * (HDIM + 1) + c];

    h2[(size_t)tn * HDIM + c] = acc;
    float s = lane32_sum(acc * sas[c]);
    float d = lane32_sum(acc * sad[c]);
    if (c == 0) {
        eab[tn] = make_float2(expf(s), expf(0.2f * s));  // exp(as2), exp(0.2*as2)
        ad2[tn] = d;
    }
}

// ---- GAT2 reduce: wave = 8 edges x 8 lanes x float4 channels; XCD-swizzled ----
__global__ void k_gat2red(const unsigned short* __restrict__ es, const int* __restrict__ row,
                          const float2* __restrict__ eab, const float* __restrict__ ad2,
                          const float* __restrict__ h2, const float* __restrict__ b2,
                          float* __restrict__ z2) {
    int b = blockIdx.x;
    int t = b & 7;            // XCD swizzle: all blocks on one XCD share one timestep
    int chunk = b >> 3;
    int wave = threadIdx.x >> 6;
    int lane = threadIdx.x & 63;
    int node = chunk * 4 + wave;          // exact: 5000 chunks * 4 waves = 20000
    int wid = t * N_NODES + node;
    int g = lane >> 3;                    // edge slot 0..7
    int l = lane & 7;                     // channel quad: channels 4l..4l+3

    int start = row[wid], end = row[wid + 1];
    float ad = ad2[wid];
    float Fa = expf(ad), Fb = expf(0.2f * ad), Et = expf(-ad);
    const float2* eabt = eab + (size_t)t * N_NODES;
    const float* h2t = h2 + (size_t)t * N_NODES * HDIM;

    float4 acc = make_float4(0.f, 0.f, 0.f, 0.f);
    float den = 0.f;
    for (int p = start + g; p < end; p += 8) {
        int s = es[p];
        float2 e = eabt[s];
        float w = (e.x > Et) ? e.x * Fa : e.y * Fb;
        float4 hv = *(const float4*)(h2t + (size_t)s * HDIM + 4 * l);
        acc.x += w * hv.x; acc.y += w * hv.y; acc.z += w * hv.z; acc.w += w * hv.w;
        den += w;
    }
#pragma unroll
    for (int off = 8; off < 64; off <<= 1) {
        acc.x += __shfl_xor(acc.x, off);
        acc.y += __shfl_xor(acc.y, off);
        acc.z += __shfl_xor(acc.z, off);
        acc.w += __shfl_xor(acc.w, off);
        den += __shfl_xor(den, off);
    }
    // self-loop (all lanes hold full sums post-reduction; harmless redundancy)
    float2 ed = eabt[node];
    float ws = (ed.x > Et) ? ed.x * Fa : ed.y * Fb;
    float4 hd = *(const float4*)(h2t + (size_t)node * HDIM + 4 * l);
    acc.x += ws * hd.x; acc.y += ws * hd.y; acc.z += ws * hd.z; acc.w += ws * hd.w;
    den += ws;

    if (g == 0) {
        float invd = 1.f / (den + 1e-16f);
        float4 o;
        o.x = eluf(acc.x * invd + b2[4 * l + 0]);
        o.y = eluf(acc.y * invd + b2[4 * l + 1]);
        o.z = eluf(acc.z * invd + b2[4 * l + 2]);
        o.w = eluf(acc.w * invd + b2[4 * l + 3]);
        *(float4*)(z2 + (size_t)wid * HDIM + 4 * l) = o;
    }
}

// ---- fused 8-step GRU + output projection ----
// 256 threads = 8 groups x 32 gate-channels; group owns GNT=4 nodes.
// Named scalars only (rule #20). Spill-avoidance (rounds 6/7/9 lessons):
//  - NO __launch_bounds__ (128-cap forced accumulator spills: 2 GB scratch)
//  - GI phase (z-dots) and GH phase (h-dots) are SEPARATE loops: <=3 weight
//    streams + <=16 accs live at once (peak ~70 regs)
//  - #pragma unroll 2: bounds the ds_read hoist window
#define GI_DECL(j) float air##j, aiz##j, ain##j;
#define GH_DECL(j) float ahr##j, ahz##j, ahn##j, hr##j;
#define GI_ACC(j) { \
    float4 zv = *(const float4*)&zls[(nb + j) * 32 + kq]; \
    air##j = fmaf(wri.w, zv.w, fmaf(wri.z, zv.z, fmaf(wri.y, zv.y, fmaf(wri.x, zv.x, air##j)))); \
    aiz##j = fmaf(wzi.w, zv.w, fmaf(wzi.z, zv.z, fmaf(wzi.y, zv.y, fmaf(wzi.x, zv.x, aiz##j)))); \
    ain##j = fmaf(wni.w, zv.w, fmaf(wni.z, zv.z, fmaf(wni.y, zv.y, fmaf(wni.x, zv.x, ain##j)))); }
#define GH_ACC(j) { \
    float4 hv = *(const float4*)&hls[(nb + j) * 32 + kq]; \
    ahr##j = fmaf(wrh.w, hv.w, fmaf(wrh.z, hv.z, fmaf(wrh.y, hv.y, fmaf(wrh.x, hv.x, ahr##j)))); \
    ahz##j = fmaf(wzh.w, hv.w, fmaf(wzh.z, hv.z, fmaf(wzh.y, hv.y, fmaf(wzh.x, hv.x, ahz##j)))); \
    ahn##j = fmaf(wnh.w, hv.w, fmaf(wnh.z, hv.z, fmaf(wnh.y, hv.y, fmaf(wnh.x, hv.x, ahn##j)))); }
#define GRU_FIN(j) { \
    float r = sigmoidf(air##j + ahr##j); \
    float z = sigmoidf(aiz##j + ahz##j); \
    float g = tanhf(ain##j + r * ahn##j); \
    hr##j = (1.f - z) * g + z * hr##j; \
    hls[(nb + j) * 32 + c] = hr##j; }

__global__ void k_gru_all(const float* __restrict__ z2, const float* __restrict__ Wih,
                          const float* __restrict__ Whh, const float* __restrict__ bih,
                          const float* __restrict__ bhh, const float* __restrict__ Wout,
                          const float* __restrict__ bout, float* __restrict__ out) {
    __shared__ float sWih[3 * HDIM * 32];  // swizzled rows, stride 32
    __shared__ float sWhh[3 * HDIM * 32];
    __shared__ float sbih[3 * HDIM], sbhh[3 * HDIM], sWout[HDIM];
    __shared__ float hls[GNB * 32];
    __shared__ float zls[GNB * 32];

    for (int i = threadIdx.x; i < 3 * HDIM * HDIM; i += 256) {
        int r = i >> 5, cc = i & 31;
        int pos = r * 32 + ((((cc >> 2) ^ (r & 7)) << 2) | (cc & 3));
        sWih[pos] = Wih[i];
        sWhh[pos] = Whh[i];
    }
    for (int i = threadIdx.x; i < 3 * HDIM; i += 256) {
        sbih[i] = bih[i];
        sbhh[i] = bhh[i];
    }
    for (int i = threadIdx.x; i < HDIM; i += 256) sWout[i] = Wout[i];
    for (int i = threadIdx.x; i < GNB * 32; i += 256) hls[i] = 0.f;
    __syncthreads();

    const int c = threadIdx.x & 31;
    const int nb = (threadIdx.x >> 5) * GNT;   // group's node base (0..28)
    const int gbase = blockIdx.x * GNB;
    const int sw = c & 7;    // row-XOR key (rows c, 32+c, 64+c share it)

    const float br = sbih[c], bz = sbih[HDIM + c], bn = sbih[2 * HDIM + c];
    const float cr = sbhh[c], cz = sbhh[HDIM + c], cn = sbhh[2 * HDIM + c];

    GI_DECL(0) GI_DECL(1) GI_DECL(2) GI_DECL(3)
    GH_DECL(0) GH_DECL(1) GH_DECL(2) GH_DECL(3)
    hr0 = hr1 = hr2 = hr3 = 0.f;

    for (int t = 0; t < T_STEPS; ++t) {
        // stage z2 tile (32 nodes x 32 ch): linear copy, one float4 per thread
        const float4* zsrc = (const float4*)(z2 + ((size_t)t * N_NODES + gbase) * HDIM);
        *(float4*)&zls[threadIdx.x * 4] = zsrc[threadIdx.x];
        __syncthreads();

        // ---- GI phase: gates from z ----
        air0 = air1 = air2 = air3 = br;
        aiz0 = aiz1 = aiz2 = aiz3 = bz;
        ain0 = ain1 = ain2 = ain3 = bn;
#pragma unroll 2
        for (int q = 0; q < 8; ++q) {
            int qa = (q ^ sw) << 2;
            int kq = q << 2;
            float4 wri = *(const float4*)&sWih[c * 32 + qa];
            float4 wzi = *(const float4*)&sWih[(HDIM + c) * 32 + qa];
            float4 wni = *(const float4*)&sWih[(2 * HDIM + c) * 32 + qa];
            GI_ACC(0) GI_ACC(1) GI_ACC(2) GI_ACC(3)
        }
        // ---- GH phase: gates from h ----
        ahr0 = ahr1 = ahr2 = ahr3 = cr;
        ahz0 = ahz1 = ahz2 = ahz3 = cz;
        ahn0 = ahn1 = ahn2 = ahn3 = cn;
#pragma unroll 2
        for (int q = 0; q < 8; ++q) {
            int qa = (q ^ sw) << 2;
            int kq = q << 2;
            float4 wrh = *(const float4*)&sWhh[c * 32 + qa];
            float4 wzh = *(const float4*)&sWhh[(HDIM + c) * 32 + qa];
            float4 wnh = *(const float4*)&sWhh[(2 * HDIM + c) * 32 + qa];
            GH_ACC(0) GH_ACC(1) GH_ACC(2) GH_ACC(3)
        }
        GRU_FIN(0) GRU_FIN(1) GRU_FIN(2) GRU_FIN(3)
        __syncthreads();  // zls reads done before next staging; hls same-wave ordered
    }

    float wo = sWout[c];
    float s0 = lane32_sum(hr0 * wo);
    float s1 = lane32_sum(hr1 * wo);
    float s2 = lane32_sum(hr2 * wo);
    float s3 = lane32_sum(hr3 * wo);
    if (c == 0) {
        float bo = bout[0];
        out[gbase + nb + 0] = s0 + bo;
        out[gbase + nb + 1] = s1 + bo;
        out[gbase + nb + 2] = s2 + bo;
        out[gbase + nb + 3] = s3 + bo;
    }
}

extern "C" void kernel_launch(void* const* d_in, const int* in_sizes, int n_in,
                              void* d_out, int out_size, void* d_ws, size_t ws_size,
                              hipStream_t stream) {
    const float* x      = (const float*)d_in[0];   // T*N
    const int* eidx     = (const int*)d_in[1];     // T*2*E
    const float* W1     = (const float*)d_in[2];
    const float* a_src1 = (const float*)d_in[3];
    const float* a_dst1 = (const float*)d_in[4];
    const float* b1     = (const float*)d_in[5];
    const float* W2     = (const float*)d_in[6];
    const float* a_src2 = (const float*)d_in[7];
    const float* a_dst2 = (const float*)d_in[8];
    const float* b2     = (const float*)d_in[9];
    const float* W_ih   = (const float*)d_in[10];
    const float* W_hh   = (const float*)d_in[11];
    const float* b_ih   = (const float*)d_in[12];
    const float* b_hh   = (const float*)d_in[13];
    const float* W_out  = (const float*)d_in[14];
    const float* b_out  = (const float*)d_in[15];
    float* out = (float*)d_out;

    char* base_ws = (char*)d_ws;
    size_t off = 0;
    auto alloc = [&](size_t bytes) {
        char* p = base_ws + off;
        off = (off + bytes + 15) & ~(size_t)15;
        return p;
    };
    int* cnt            = (int*)alloc((size_t)TN * 4);
    int* row            = (int*)alloc((size_t)(TN + 1) * 4);
    int* bsum           = (int*)alloc((size_t)SCAN_BLOCKS * 4);
    int* bpre           = (int*)alloc((size_t)SCAN_BLOCKS * 4);
    float* inv          = (float*)alloc((size_t)TN * 2 * 4);
    float* h2           = (float*)alloc((size_t)TN * HDIM * 4);
    float2* eab         = (float2*)alloc((size_t)TN * 8);
    float* ad2          = (float*)alloc((size_t)TN * 4);
    float* z2           = (float*)alloc((size_t)TN * HDIM * 4);
    float* S4           = (float*)alloc(16);
    unsigned short* es  = (unsigned short*)alloc((size_t)TE * 2);
    unsigned char* rank = (unsigned char*)alloc((size_t)TE);
    // hist/base alias h2's region: CSR build completes before k_node1 writes h2
    // (stream-ordered). Each is T*GB*NPAIR ints = 10.24 MB; h2 = 20.48 MB.
    int* hist = (int*)h2;
    int* bbase = hist + (size_t)T_STEPS * GB * NPAIR;

    const int B = 256;
    k_prep<<<1, 64, 0, stream>>>(W1, a_src1, a_dst1, S4);

    dim3 hgrid(GB, T_STEPS);
    k_hist<<<hgrid, 512, 0, stream>>>(eidx, hist, rank);
    k_blkpre<<<(T_STEPS * NPAIR + B - 1) / B, B, 0, stream>>>(hist, bbase, cnt);
    k_scan_a<<<SCAN_BLOCKS, B, 0, stream>>>(cnt, bsum);
    k_scan_b<<<1, B, 0, stream>>>(bsum, bpre);
    k_scan_c<<<SCAN_BLOCKS, B, 0, stream>>>(cnt, bpre, row);
    dim3 egrid((E_EDGES + B - 1) / B, T_STEPS);
    k_scatter<<<egrid, B, 0, stream>>>(eidx, rank, row, bbase, es);

    k_gat1red<<<TN / 4, B, 0, stream>>>(es, row, x, S4, inv);
    k_node1<<<TN / NPB, B, 0, stream>>>(inv, W1, b1, W2, a_src2, a_dst2, h2, eab, ad2);
    k_gat2red<<<TN / 4, B, 0, stream>>>(es, row, eab, ad2, h2, b2, z2);

    k_gru_all<<<N_NODES / GNB, B, 0, stream>>>(z2, W_ih, W_hh, b_ih, b_hh, W_out, b_out, out);
}